// Round 1
// baseline (487.157 us; speedup 1.0000x reference)
//
#include <hip/hip_runtime.h>

#define D_SZ 768
#define N_SZ 50000
#define L_SZ 28
#define B_SZ 1024
#define NP   50048   // 391 * 128 (padded N)
#define NT   391     // n-tiles of 128

typedef __bf16 bf16x8 __attribute__((ext_vector_type(8)));
typedef float f32x4 __attribute__((ext_vector_type(4)));
typedef unsigned short u16x8 __attribute__((ext_vector_type(8)));

__device__ __forceinline__ unsigned short f2bf(float f) {
  union { float f; unsigned u; } v; v.f = f;
  unsigned r = v.u + 0x7FFFu + ((v.u >> 16) & 1u);
  return (unsigned short)(r >> 16);
}
__device__ __forceinline__ float bf2f(unsigned short u) {
  union { unsigned u; float f; } v; v.u = ((unsigned)u) << 16; return v.f;
}

// ---------------------------------------------------------------------------
// Projection GEMM: Y[M][768] (bf16, unnormalized) = X[M][768] @ W[768][768]^T
// 128x128 tile, BK=32, 4 waves (2x2), f32->bf16 convert-on-stage.
// ---------------------------------------------------------------------------
__global__ __launch_bounds__(256, 2)
void proj_gemm(const float* __restrict__ X, const float* __restrict__ W,
               unsigned short* __restrict__ Y, int Mvalid)
{
  __shared__ __align__(16) unsigned short As[128 * 32];
  __shared__ __align__(16) unsigned short Bs[128 * 32];
  const int tid = threadIdx.x;
  const int m0 = blockIdx.y * 128;
  const int o0 = blockIdx.x * 128;
  const int w = tid >> 6, lane = tid & 63;
  const int wr = w >> 1, wc = w & 1;
  const int fr = lane & 15, fq = lane >> 4;
  const int fk = fq << 3;

  f32x4 acc[4][4] = {};

  for (int kk = 0; kk < D_SZ; kk += 32) {
#pragma unroll
    for (int i = 0; i < 2; ++i) {
      const int idx = tid + i * 256;     // 0..511
      const int row = idx >> 2;          // 0..127
      const int c8 = (idx & 3) << 3;     // 0,8,16,24
      float4 a0, a1;
      if (m0 + row < Mvalid) {
        const float* p = X + (size_t)(m0 + row) * D_SZ + kk + c8;
        a0 = *(const float4*)p;
        a1 = *(const float4*)(p + 4);
      } else {
        a0 = make_float4(0.f, 0.f, 0.f, 0.f); a1 = a0;
      }
      u16x8 av;
      av[0] = f2bf(a0.x); av[1] = f2bf(a0.y); av[2] = f2bf(a0.z); av[3] = f2bf(a0.w);
      av[4] = f2bf(a1.x); av[5] = f2bf(a1.y); av[6] = f2bf(a1.z); av[7] = f2bf(a1.w);
      *(u16x8*)&As[row * 32 + c8] = av;

      const float* q = W + (size_t)(o0 + row) * D_SZ + kk + c8;
      const float4 b0 = *(const float4*)q;
      const float4 b1 = *(const float4*)(q + 4);
      u16x8 bv;
      bv[0] = f2bf(b0.x); bv[1] = f2bf(b0.y); bv[2] = f2bf(b0.z); bv[3] = f2bf(b0.w);
      bv[4] = f2bf(b1.x); bv[5] = f2bf(b1.y); bv[6] = f2bf(b1.z); bv[7] = f2bf(b1.w);
      *(u16x8*)&Bs[row * 32 + c8] = bv;
    }
    __syncthreads();
    bf16x8 af[4], bfv[4];
#pragma unroll
    for (int i = 0; i < 4; ++i) {
      af[i]  = *(const bf16x8*)&As[(wr * 64 + i * 16 + fr) * 32 + fk];
      bfv[i] = *(const bf16x8*)&Bs[(wc * 64 + i * 16 + fr) * 32 + fk];
    }
#pragma unroll
    for (int mi = 0; mi < 4; ++mi)
#pragma unroll
      for (int ni = 0; ni < 4; ++ni)
        acc[mi][ni] = __builtin_amdgcn_mfma_f32_16x16x32_bf16(af[mi], bfv[ni], acc[mi][ni], 0, 0, 0);
    __syncthreads();
  }
#pragma unroll
  for (int mi = 0; mi < 4; ++mi)
#pragma unroll
    for (int ni = 0; ni < 4; ++ni)
#pragma unroll
      for (int r = 0; r < 4; ++r) {
        const int row = m0 + wr * 64 + mi * 16 + fq * 4 + r;
        const int col = o0 + wc * 64 + ni * 16 + fr;
        Y[(size_t)row * D_SZ + col] = f2bf(acc[mi][ni][r]);
      }
}

// ---------------------------------------------------------------------------
// In-place row L2-normalize of bf16 [Mtotal][768]; one wave per row.
// Pad rows (all zero) stay zero (0 * 1e12 == 0).
// ---------------------------------------------------------------------------
__global__ void rownorm(unsigned short* __restrict__ Y, int Mtotal)
{
  const int row = blockIdx.x * 4 + (threadIdx.x >> 6);
  const int lane = threadIdx.x & 63;
  if (row >= Mtotal) return;
  unsigned short* p = Y + (size_t)row * D_SZ + lane * 12;
  ushort4 v[3];
  v[0] = *(const ushort4*)p;
  v[1] = *(const ushort4*)(p + 4);
  v[2] = *(const ushort4*)(p + 8);
  float f[12];
#pragma unroll
  for (int c = 0; c < 3; ++c) {
    f[c * 4 + 0] = bf2f(v[c].x); f[c * 4 + 1] = bf2f(v[c].y);
    f[c * 4 + 2] = bf2f(v[c].z); f[c * 4 + 3] = bf2f(v[c].w);
  }
  float ss = 0.f;
#pragma unroll
  for (int i = 0; i < 12; ++i) ss += f[i] * f[i];
#pragma unroll
  for (int o = 32; o; o >>= 1) ss += __shfl_xor(ss, o);
  const float inv = 1.0f / fmaxf(sqrtf(ss), 1e-12f);
#pragma unroll
  for (int c = 0; c < 3; ++c) {
    ushort4 ov;
    ov.x = f2bf(f[c * 4 + 0] * inv); ov.y = f2bf(f[c * 4 + 1] * inv);
    ov.z = f2bf(f[c * 4 + 2] * inv); ov.w = f2bf(f[c * 4 + 3] * inv);
    *(ushort4*)(p + c * 4) = ov;
  }
}

// ---------------------------------------------------------------------------
// Build excT bf16 [32][NP]: excT[l][n] = ex_classes[n][l] (zero-padded).
// ---------------------------------------------------------------------------
__global__ void excT_prep(const float* __restrict__ exc, unsigned short* __restrict__ excT)
{
  __shared__ float lds[64][29];
  const int n0 = blockIdx.x * 64;
  const int tid = threadIdx.x;
  for (int i = tid; i < 64 * L_SZ; i += 256) {
    const int n = i / L_SZ, l = i % L_SZ;
    lds[n][l] = (n0 + n < N_SZ) ? exc[(size_t)(n0 + n) * L_SZ + l] : 0.0f;
  }
  __syncthreads();
  for (int i = tid; i < 32 * 64; i += 256) {
    const int l = i >> 6, n = i & 63;
    const float v = (l < L_SZ) ? lds[n][l] : 0.0f;
    excT[(size_t)l * NP + n0 + n] = f2bf(v);
  }
}

// ---------------------------------------------------------------------------
// Per-class exemplar counts: counts[l] = sum_n ex_classes[n][l].
// ---------------------------------------------------------------------------
__global__ void countsk(const float* __restrict__ exc, float* __restrict__ counts)
{
  const int l = blockIdx.x;
  float c = 0.f;
  for (int n = threadIdx.x; n < N_SZ; n += 256) c += exc[(size_t)n * L_SZ + l];
  __shared__ float red[256];
  red[threadIdx.x] = c;
  __syncthreads();
  for (int s = 128; s; s >>= 1) {
    if (threadIdx.x < s) red[threadIdx.x] += red[threadIdx.x + s];
    __syncthreads();
  }
  if (threadIdx.x == 0) counts[l] = red[0];
}

// ---------------------------------------------------------------------------
// Fused s-GEMM: per 128x128 tile, s = fn @ exfn^T (K=768), a = s^3 -> swizzled
// LDS, then echo_part += a @ excT^T (K=128) in AGPRs across 8 tiles; atomics.
// ---------------------------------------------------------------------------
__global__ __launch_bounds__(256, 2)
void echo_gemm(const unsigned short* __restrict__ fn,
               const unsigned short* __restrict__ exfn,
               const unsigned short* __restrict__ excT,
               float* __restrict__ echo)
{
  __shared__ __align__(16) unsigned short As[128 * 32];
  __shared__ __align__(16) unsigned short Bs[128 * 32];
  __shared__ __align__(16) unsigned short Al[128 * 128];
  const int tid = threadIdx.x;
  const int w = tid >> 6, lane = tid & 63;
  const int wr = w >> 1, wc = w & 1;
  const int m0 = blockIdx.y * 128;
  const int fr = lane & 15, fq = lane >> 4;
  const int fk = fq << 3;
  const int srow = lane >> 2;
  const int scol = (lane & 3) << 3;

  f32x4 acc2[2][2] = {};

  for (int ti = 0; ti < 8; ++ti) {
    const int t = blockIdx.x * 8 + ti;
    if (t >= NT) break;
    const int n0 = t * 128;
    f32x4 acc[4][4] = {};
    for (int kk = 0; kk < D_SZ; kk += 32) {
#pragma unroll
      for (int i = 0; i < 2; ++i) {
        const int chunk = w * 2 + i;
        const int row = chunk * 16 + srow;
        const unsigned short* ga = fn + (size_t)(m0 + row) * D_SZ + kk + scol;
        const unsigned short* gb = exfn + (size_t)(n0 + row) * D_SZ + kk + scol;
        __builtin_amdgcn_global_load_lds((const __attribute__((address_space(1))) void*)ga,
                                         (__attribute__((address_space(3))) void*)&As[chunk * 512],
                                         16, 0, 0);
        __builtin_amdgcn_global_load_lds((const __attribute__((address_space(1))) void*)gb,
                                         (__attribute__((address_space(3))) void*)&Bs[chunk * 512],
                                         16, 0, 0);
      }
      __syncthreads();
      bf16x8 af[4], bfv[4];
#pragma unroll
      for (int i = 0; i < 4; ++i) {
        af[i]  = *(const bf16x8*)&As[(wr * 64 + i * 16 + fr) * 32 + fk];
        bfv[i] = *(const bf16x8*)&Bs[(wc * 64 + i * 16 + fr) * 32 + fk];
      }
#pragma unroll
      for (int mi = 0; mi < 4; ++mi)
#pragma unroll
        for (int ni = 0; ni < 4; ++ni)
          acc[mi][ni] = __builtin_amdgcn_mfma_f32_16x16x32_bf16(af[mi], bfv[ni], acc[mi][ni], 0, 0, 0);
      __syncthreads();
    }
    // cube and stage a = s^3 into XOR-swizzled LDS tile [b][n]
#pragma unroll
    for (int mi = 0; mi < 4; ++mi)
#pragma unroll
      for (int ni = 0; ni < 4; ++ni)
#pragma unroll
        for (int r = 0; r < 4; ++r) {
          const int b = wr * 64 + mi * 16 + fq * 4 + r;
          const int n = wc * 64 + ni * 16 + fr;
          const float s = acc[mi][ni][r];
          const unsigned byte = (((unsigned)(b * 128 + n)) << 1) ^ ((unsigned)(b & 7) << 4);
          *(unsigned short*)((char*)Al + byte) = f2bf(s * s * s);
        }
    __syncthreads();
    // stage 2: echo_part[b][cls] += a[b][n] * excT[cls][n]; wave w owns rows w*32..+31
#pragma unroll
    for (int kk2 = 0; kk2 < 128; kk2 += 32) {
      bf16x8 pa[2], pb[2];
#pragma unroll
      for (int i = 0; i < 2; ++i) {
        const int b = w * 32 + i * 16 + fr;
        const unsigned byte = (((unsigned)(b * 128 + kk2 + fk)) << 1) ^ ((unsigned)(b & 7) << 4);
        pa[i] = *(const bf16x8*)((const char*)Al + byte);
        const int cls = i * 16 + fr;
        pb[i] = *(const bf16x8*)(excT + (size_t)cls * NP + n0 + kk2 + fk);
      }
#pragma unroll
      for (int mi = 0; mi < 2; ++mi)
#pragma unroll
        for (int ni = 0; ni < 2; ++ni)
          acc2[mi][ni] = __builtin_amdgcn_mfma_f32_16x16x32_bf16(pa[mi], pb[ni], acc2[mi][ni], 0, 0, 0);
    }
    __syncthreads();
  }
#pragma unroll
  for (int mi = 0; mi < 2; ++mi)
#pragma unroll
    for (int ni = 0; ni < 2; ++ni)
#pragma unroll
      for (int r = 0; r < 4; ++r) {
        const int b = w * 32 + mi * 16 + fq * 4 + r;
        const int cls = ni * 16 + fr;
        if (cls < L_SZ)
          atomicAdd(&echo[(size_t)(m0 + b) * L_SZ + cls], acc2[mi][ni][r]);
      }
}

// ---------------------------------------------------------------------------
// Finalize: echo/counts -> neg_dists (vs real class_reps) -> BCE loss.
// One block, 1024 threads (thread == batch row).
// ---------------------------------------------------------------------------
__global__ __launch_bounds__(1024)
void finalize(const float* __restrict__ echo, const float* __restrict__ counts,
              const float* __restrict__ labels, const float* __restrict__ creps,
              float* __restrict__ out)
{
  __shared__ float C[L_SZ * L_SZ];
  __shared__ float cnt[L_SZ];
  __shared__ float red[16];
  const int tid = threadIdx.x;
  if (tid < L_SZ * L_SZ) C[tid] = creps[tid];
  if (tid >= 896 && tid < 896 + L_SZ) cnt[tid - 896] = counts[tid - 896];
  __syncthreads();
  float e[L_SZ];
#pragma unroll
  for (int l = 0; l < L_SZ; ++l) e[l] = echo[tid * L_SZ + l] / cnt[l];
  float lsum = 0.f;
  for (int j = 0; j < L_SZ; ++j) {
    float d2 = 0.f;
#pragma unroll
    for (int l = 0; l < L_SZ; ++l) { const float df = e[l] - C[j * L_SZ + l]; d2 += df * df; }
    const float nd = -sqrtf(d2);
    out[1 + tid * L_SZ + j] = nd;
    const float y = labels[tid * L_SZ + j];
    const float sp = fmaxf(nd, 0.f) + log1pf(expf(-fabsf(nd)));
    lsum += sp - nd * y;
  }
#pragma unroll
  for (int o = 32; o; o >>= 1) lsum += __shfl_xor(lsum, o);
  if ((tid & 63) == 0) red[tid >> 6] = lsum;
  __syncthreads();
  if (tid < 16) {
    float v = red[tid];
#pragma unroll
    for (int o = 8; o; o >>= 1) v += __shfl_xor(v, o);
    if (tid == 0) out[0] = v * (1.0f / (B_SZ * L_SZ));
  }
}

extern "C" void kernel_launch(void* const* d_in, const int* in_sizes, int n_in,
                              void* d_out, int out_size, void* d_ws, size_t ws_size,
                              hipStream_t stream)
{
  (void)in_sizes; (void)n_in; (void)out_size;
  const float* features = (const float*)d_in[0];
  const float* labels   = (const float*)d_in[1];
  const float* W_g      = (const float*)d_in[2];
  const float* ex_feat  = (const float*)d_in[3];
  const float* ex_cls   = (const float*)d_in[4];
  const float* creps    = (const float*)d_in[5];
  float* out = (float*)d_out;

  // workspace layout (bytes)
  const size_t OFF_EXFN = 0;                               // NP*768*2 = 76,873,728
  const size_t OFF_FN   = OFF_EXFN + (size_t)NP * D_SZ * 2;       // + 1,572,864
  const size_t OFF_EXCT = OFF_FN + (size_t)B_SZ * D_SZ * 2;       // + 3,203,072
  const size_t OFF_ECHO = OFF_EXCT + (size_t)32 * NP * 2;         // + 114,688
  const size_t OFF_CNT  = OFF_ECHO + (size_t)B_SZ * L_SZ * 4;     // + 112
  const size_t NEED = OFF_CNT + (size_t)L_SZ * 4;
  if (ws_size < NEED) return;  // visible as stub-like failure if ws too small

  char* ws = (char*)d_ws;
  unsigned short* exfn = (unsigned short*)(ws + OFF_EXFN);
  unsigned short* fnb  = (unsigned short*)(ws + OFF_FN);
  unsigned short* excT = (unsigned short*)(ws + OFF_EXCT);
  float* echo   = (float*)(ws + OFF_ECHO);
  float* counts = (float*)(ws + OFF_CNT);

  hipMemsetAsync(echo, 0, (size_t)B_SZ * L_SZ * sizeof(float), stream);

  excT_prep<<<dim3(NP / 64), 256, 0, stream>>>(ex_cls, excT);
  countsk<<<dim3(L_SZ), 256, 0, stream>>>(ex_cls, counts);
  proj_gemm<<<dim3(6, B_SZ / 128), 256, 0, stream>>>(features, W_g, fnb, B_SZ);
  proj_gemm<<<dim3(6, NP / 128), 256, 0, stream>>>(ex_feat, W_g, exfn, N_SZ);
  rownorm<<<dim3(B_SZ / 4), 256, 0, stream>>>(fnb, B_SZ);
  rownorm<<<dim3(NP / 4), 256, 0, stream>>>(exfn, NP);
  echo_gemm<<<dim3(49, 8), 256, 0, stream>>>(fnb, exfn, excT, echo);
  finalize<<<dim3(1), 1024, 0, stream>>>(echo, counts, labels, creps, out);
}